// Round 20
// baseline (59.712 us; speedup 1.0000x reference)
//
#include <hip/hip_runtime.h>

#define NB 16384
#define TT 10
#define DIN 256
#define HH 16
#define NG 64      // 4*H
#define NF 160     // T*H

typedef __attribute__((ext_vector_type(8))) _Float16 half8;
typedef __attribute__((ext_vector_type(4))) _Float16 half4;
typedef __attribute__((ext_vector_type(4))) float f32x4;
typedef unsigned int u32;

__device__ __forceinline__ void gld16(const float* g, float* l) {
    __builtin_amdgcn_global_load_lds(
        (const __attribute__((address_space(1))) u32*)g,
        (__attribute__((address_space(3))) u32*)l, 16, 0, 0);
}
__device__ __forceinline__ float sigf(float x) { return 1.0f / (1.0f + __expf(-x)); }
__device__ __forceinline__ float tanhf_(float x) {
    float e = __expf(2.0f * x);
    return 1.0f - 2.0f / (e + 1.0f);
}

// K1: MEGAFUSED proj + 2-layer LSTM (R19 math, self-prep) with COALESCED
// LDS-staged x loads: per K-chunk (16 samples x 128 floats = 8KB), 8
// global_load_lds each reading 2 contiguous 512B segments (vs R19's
// 64-granule scatter per instruction). Per-wave private double buffer,
// counted vmcnt (8-16KB always in flight), no workgroup barriers in loop.
// Both-sides XOR swizzle (byte ^= (sample&7)<<4) -> ~2-way (free) LDS reads.
__global__ __launch_bounds__(256, 1) void k_mega(
        const float* __restrict__ x, const float* __restrict__ wih0,
        const float* __restrict__ bih0, const float* __restrict__ bhh0,
        const float* __restrict__ whh0, const float* __restrict__ wih1,
        const float* __restrict__ whh1, const float* __restrict__ bi1,
        const float* __restrict__ bh1, _Float16* __restrict__ flatT) {
    __shared__ half8 Bl[2048];        // 32 KB Wih0 fragments
    __shared__ float xs[4][2][2048];  // 64 KB: 4 waves x 2 chunk-buffers x 8KB
    const int tid = threadIdx.x;
    const int l = tid & 63;
    const int wv = tid >> 6;

    // ---- self-prep: Wih0 fragments -> Bl (validated mapping) ----
    #pragma unroll
    for (int q = 0; q < 8; ++q) {
        const int fi = q * 256 + tid;
        const int c = fi >> 9;
        const int s = (fi >> 6) & 7;
        const int ll = fi & 63;
        const int row = c * 16 + (ll & 15);
        const int k0 = s * 32 + ((ll >> 4) << 3);
        const float* wp = wih0 + (size_t)row * DIN + k0;
        float4 a = *(const float4*)wp;
        float4 b = *(const float4*)(wp + 4);
        half8 h;
        h[0] = (_Float16)a.x; h[1] = (_Float16)a.y;
        h[2] = (_Float16)a.z; h[3] = (_Float16)a.w;
        h[4] = (_Float16)b.x; h[5] = (_Float16)b.y;
        h[6] = (_Float16)b.z; h[7] = (_Float16)b.w;
        Bl[fi] = h;
    }

    // ---- recurrence fragments + fused biases (validated k_prep math) ----
    half4 w0f[4], w1f[4], w2f[4];
    f32x4 b0[4], b1[4];
    #pragma unroll
    for (int c = 0; c < 4; ++c) {
        const int mrow = c * 16 + (l & 15);
        const int mk = (l >> 4) << 2;
        float4 v0 = *(const float4*)(whh0 + (size_t)mrow * HH + mk);
        w0f[c][0] = (_Float16)v0.x; w0f[c][1] = (_Float16)v0.y;
        w0f[c][2] = (_Float16)v0.z; w0f[c][3] = (_Float16)v0.w;
        float4 v1 = *(const float4*)(wih1 + (size_t)mrow * HH + mk);
        w1f[c][0] = (_Float16)v1.x; w1f[c][1] = (_Float16)v1.y;
        w1f[c][2] = (_Float16)v1.z; w1f[c][3] = (_Float16)v1.w;
        float4 v2 = *(const float4*)(whh1 + (size_t)mrow * HH + mk);
        w2f[c][0] = (_Float16)v2.x; w2f[c][1] = (_Float16)v2.y;
        w2f[c][2] = (_Float16)v2.z; w2f[c][3] = (_Float16)v2.w;
        const int bofs = c * 16 + mk;
        float4 vi0 = *(const float4*)(bih0 + bofs);
        float4 vh0 = *(const float4*)(bhh0 + bofs);
        b0[c][0] = vi0.x + vh0.x; b0[c][1] = vi0.y + vh0.y;
        b0[c][2] = vi0.z + vh0.z; b0[c][3] = vi0.w + vh0.w;
        float4 vi1 = *(const float4*)(bi1 + bofs);
        float4 vh1 = *(const float4*)(bh1 + bofs);
        b1[c][0] = vi1.x + vh1.x; b1[c][1] = vi1.y + vh1.y;
        b1[c][2] = vi1.z + vh1.z; b1[c][3] = vi1.w + vh1.w;
    }
    __syncthreads();   // Bl ready; vm counter clean after barrier

    const int sb = blockIdx.x * 4 + wv;              // sample-group 0..1023
    float* xsbuf = &xs[wv][0][0];
    const int lsmp = l & 15;                          // lane's sample for reads
    const int rswz = (lsmp & 7) << 4;                 // read-side XOR

    half4 h0f, h1f;
    #pragma unroll
    for (int j = 0; j < 4; ++j) { h0f[j] = (_Float16)0.0f; h1f[j] = (_Float16)0.0f; }
    f32x4 cs0 = (f32x4)0.0f, cs1 = (f32x4)0.0f;

// issue chunk c (0/1) of step t into buffer c: 8 gld16, each = 2 contiguous
// 512B segments (samples 2i, 2i+1). Global source pre-swizzled per-lane.
#define ISSUE(t, c)                                                            \
    {                                                                          \
        float* dst = xsbuf + (c) * 2048;                                       \
        _Pragma("unroll")                                                      \
        for (int i = 0; i < 8; ++i) {                                          \
            const int smp = 2 * i + (l >> 5);                                  \
            const int inseg = ((l & 31) * 16) ^ ((smp & 7) << 4);              \
            gld16(x + (size_t)(sb * 16 + smp) * (TT * DIN)                     \
                    + (t) * DIN + (c) * 128 + (inseg >> 2),                    \
                  dst + i * 256);                                              \
        }                                                                      \
    }

#define WAITVM(n)                                                              \
    asm volatile("s_waitcnt vmcnt(" #n ")" ::: "memory");                      \
    __builtin_amdgcn_sched_barrier(0);
#define FENCELGKM                                                              \
    asm volatile("s_waitcnt lgkmcnt(0)" ::: "memory");                         \
    __builtin_amdgcn_sched_barrier(0);

// compute one chunk (4 K-slices) from buffer c, accumulating into ac0.
// s0base = c*4 selects the Bl fragment slice range.
#define CHUNK(c, s0base, ac0)                                                  \
        _Pragma("unroll")                                                      \
        for (int sp = 0; sp < 4; ++sp) {                                       \
            const int woff = sp * 128 + ((l >> 4) << 5);                       \
            const char* segp = (const char*)(xsbuf + (c) * 2048) + lsmp * 512; \
            f32x4 va = *(const f32x4*)(segp + (woff ^ rswz));                  \
            f32x4 vb = *(const f32x4*)(segp + ((woff + 16) ^ rswz));           \
            float fv[8] = {va.x, va.y, va.z, va.w, vb.x, vb.y, vb.z, vb.w};    \
            half8 xh, xl;                                                      \
            _Pragma("unroll")                                                  \
            for (int j = 0; j < 8; ++j) {                                      \
                _Float16 hi = (_Float16)fv[j];                                 \
                xh[j] = hi;                                                    \
                xl[j] = (_Float16)(fv[j] - (float)hi);                         \
            }                                                                  \
            _Pragma("unroll")                                                  \
            for (int cc = 0; cc < 4; ++cc) {                                   \
                half8 wf = Bl[(cc * 8 + (s0base) + sp) * 64 + l];              \
                ac0[cc] = __builtin_amdgcn_mfma_f32_16x16x32_f16(wf, xh, ac0[cc], 0, 0, 0); \
                ac0[cc] = __builtin_amdgcn_mfma_f32_16x16x32_f16(wf, xl, ac0[cc], 0, 0, 0); \
            }                                                                  \
        }

// recurrence (R19-exact): h-feedback MFMAs + activations + flatT store
#define REC(t, ac0)                                                            \
        _Pragma("unroll")                                                      \
        for (int c = 0; c < 4; ++c)                                            \
            ac0[c] = __builtin_amdgcn_mfma_f32_16x16x16f16(w0f[c], h0f, ac0[c], 0, 0, 0); \
        f32x4 h0v;                                                             \
        _Pragma("unroll")                                                      \
        for (int r = 0; r < 4; ++r) {                                          \
            float iv = sigf(ac0[0][r]), fg = sigf(ac0[1][r]);                  \
            float gv = tanhf_(ac0[2][r]), ov = sigf(ac0[3][r]);                \
            cs0[r] = fg * cs0[r] + iv * gv;                                    \
            h0v[r] = ov * tanhf_(cs0[r]);                                      \
        }                                                                      \
        h0f[0] = (_Float16)h0v[0]; h0f[1] = (_Float16)h0v[1];                  \
        h0f[2] = (_Float16)h0v[2]; h0f[3] = (_Float16)h0v[3];                  \
        f32x4 ac1[4] = {b1[0], b1[1], b1[2], b1[3]};                           \
        _Pragma("unroll")                                                      \
        for (int c = 0; c < 4; ++c) {                                          \
            ac1[c] = __builtin_amdgcn_mfma_f32_16x16x16f16(w1f[c], h0f, ac1[c], 0, 0, 0); \
            ac1[c] = __builtin_amdgcn_mfma_f32_16x16x16f16(w2f[c], h1f, ac1[c], 0, 0, 0); \
        }                                                                      \
        f32x4 h1v;                                                             \
        _Pragma("unroll")                                                      \
        for (int r = 0; r < 4; ++r) {                                          \
            float iv = sigf(ac1[0][r]), fg = sigf(ac1[1][r]);                  \
            float gv = tanhf_(ac1[2][r]), ov = sigf(ac1[3][r]);                \
            cs1[r] = fg * cs1[r] + iv * gv;                                    \
            h1v[r] = ov * tanhf_(cs1[r]);                                      \
        }                                                                      \
        h1f[0] = (_Float16)h1v[0]; h1f[1] = (_Float16)h1v[1];                  \
        h1f[2] = (_Float16)h1v[2]; h1f[3] = (_Float16)h1v[3];                  \
        _Pragma("unroll")                                                      \
        for (int r = 0; r < 4; ++r)                                            \
            flatT[(size_t)((t) * 16 + ((l >> 4) << 2) + r) * NB + sb * 16 + lsmp] = (_Float16)h1v[r];

// one timestep: wait A-chunk -> compute -> refill A; wait B -> compute ->
// refill B; recurrence overlaps the 16 outstanding loads.
#define STEP(t, WA, WB)                                                        \
    {                                                                          \
        f32x4 ac0[4] = {b0[0], b0[1], b0[2], b0[3]};                           \
        WAITVM(WA)                                                             \
        CHUNK(0, 0, ac0)                                                       \
        FENCELGKM                                                              \
        if ((t) < 9) ISSUE((t) + 1, 0)                                         \
        WAITVM(WB)                                                             \
        CHUNK(1, 4, ac0)                                                       \
        FENCELGKM                                                              \
        if ((t) < 9) ISSUE((t) + 1, 1)                                         \
        REC(t, ac0)                                                            \
    }

    ISSUE(0, 0)
    ISSUE(0, 1)        // 16 outstanding

    STEP(0, 8, 8)
    STEP(1, 8, 8)
    STEP(2, 8, 8)
    STEP(3, 8, 8)
    STEP(4, 8, 8)
    STEP(5, 8, 8)
    STEP(6, 8, 8)
    STEP(7, 8, 8)
    STEP(8, 8, 8)
    STEP(9, 8, 0)
#undef STEP
#undef REC
#undef CHUNK
#undef ISSUE
#undef WAITVM
#undef FENCELGKM
}

// K2: BN stats directly from column-major flatT (coalesced).
__global__ __launch_bounds__(256) void k_bn(
        const _Float16* __restrict__ flatT, const float* __restrict__ gamma,
        const float* __restrict__ beta, float* __restrict__ scale,
        float* __restrict__ shift) {
    const int f = blockIdx.x;
    const int tid = threadIdx.x;
    const _Float16* col = flatT + (size_t)f * NB;
    float s = 0.0f, q = 0.0f;
    #pragma unroll 8
    for (int i = tid; i < NB; i += 256) {
        float v = (float)col[i];
        s += v; q += v * v;
    }
    #pragma unroll
    for (int o = 32; o > 0; o >>= 1) {
        s += __shfl_down(s, o, 64);
        q += __shfl_down(q, o, 64);
    }
    __shared__ float rs[4], rq[4];
    const int wv = tid >> 6;
    if ((tid & 63) == 0) { rs[wv] = s; rq[wv] = q; }
    __syncthreads();
    if (tid == 0) {
        float S = rs[0] + rs[1] + rs[2] + rs[3];
        float Q = rq[0] + rq[1] + rq[2] + rq[3];
        float mean = S * (1.0f / NB);
        float var = Q * (1.0f / NB) - mean * mean;
        float sc = gamma[f] * rsqrtf(var + 1e-5f);
        scale[f] = sc;
        shift[f] = beta[f] - mean * sc;
    }
}

// K3: BN-apply + LeakyReLU + concat + FC(162->2) + softmax.
__global__ __launch_bounds__(256) void k_fc(
        const _Float16* __restrict__ flatT, const float* __restrict__ scale,
        const float* __restrict__ shift, const float* __restrict__ ag,
        const float* __restrict__ fcw, const float* __restrict__ fcb,
        float* __restrict__ out) {
    const int smp = blockIdx.x * 256 + threadIdx.x;
    float p0 = 0.0f, p1 = 0.0f;
    #pragma unroll 8
    for (int f = 0; f < NF; ++f) {
        float xn = (float)flatT[(size_t)f * NB + smp] * scale[f] + shift[f];
        float a = xn >= 0.0f ? xn : 0.01f * xn;
        p0 += a * fcw[f];
        p1 += a * fcw[162 + f];
    }
    float a0 = ag[(size_t)smp * 2 + 0], a1 = ag[(size_t)smp * 2 + 1];
    float l0 = p0 + a0 * fcw[160] + a1 * fcw[161] + fcb[0];
    float l1 = p1 + a0 * fcw[162 + 160] + a1 * fcw[162 + 161] + fcb[1];
    float m = fmaxf(l0, l1);
    float e0 = __expf(l0 - m), e1 = __expf(l1 - m);
    float inv = 1.0f / (e0 + e1);
    out[(size_t)smp * 2 + 0] = e0 * inv;
    out[(size_t)smp * 2 + 1] = e1 * inv;
}

extern "C" void kernel_launch(void* const* d_in, const int* in_sizes, int n_in,
                              void* d_out, int out_size, void* d_ws, size_t ws_size,
                              hipStream_t stream) {
    const float* x     = (const float*)d_in[0];
    const float* ag    = (const float*)d_in[1];
    const float* wih0  = (const float*)d_in[2];
    const float* whh0  = (const float*)d_in[3];
    const float* bih0  = (const float*)d_in[4];
    const float* bhh0  = (const float*)d_in[5];
    const float* wih1  = (const float*)d_in[6];
    const float* whh1  = (const float*)d_in[7];
    const float* bih1  = (const float*)d_in[8];
    const float* bhh1  = (const float*)d_in[9];
    const float* gamma = (const float*)d_in[10];
    const float* beta  = (const float*)d_in[11];
    const float* fcw   = (const float*)d_in[12];
    const float* fcb   = (const float*)d_in[13];
    float* out = (float*)d_out;

    float* ws = (float*)d_ws;
    _Float16* flatT = (_Float16*)ws;   // [NF][NB] = 2,621,440 halfs = 1,310,720 f32 slots
    float* scale = ws + 1310720;       // 160 (after flatT's f32 footprint)
    float* shift = ws + 1310880;       // 160

    k_mega<<<dim3(256), dim3(256), 0, stream>>>(x, wih0, bih0, bhh0, whh0,
                                                wih1, whh1, bih1, bhh1, flatT);
    k_bn<<<dim3(NF),    dim3(256), 0, stream>>>(flatT, gamma, beta, scale, shift);
    k_fc<<<dim3(64),    dim3(256), 0, stream>>>(flatT, scale, shift, ag, fcw, fcb, out);
}

// Round 21
// 53.799 us; speedup vs baseline: 1.1099x; 1.1099x over previous
//
#include <hip/hip_runtime.h>

#define NB 16384
#define TT 10
#define DIN 256
#define HH 16
#define NG 64      // 4*H
#define NF 160     // T*H

typedef __attribute__((ext_vector_type(8))) _Float16 half8;
typedef __attribute__((ext_vector_type(4))) _Float16 half4;
typedef __attribute__((ext_vector_type(4))) float f32x4;

__device__ __forceinline__ float sigf(float x) { return 1.0f / (1.0f + __expf(-x)); }
__device__ __forceinline__ float tanhf_(float x) {
    float e = __expf(2.0f * x);
    return 1.0f - 2.0f / (e + 1.0f);
}

// K1: MEGAFUSED proj + 2-layer LSTM (R19-exact, best verified 54.7us).
// Self-prep: block converts Wih0 into LDS fragments + recurrence fragments/
// biases per-thread. One wave = 16 samples; C[gate][sample] orientation;
// identity h-feedback layout; double-buffered register prefetch of x.
__global__ __launch_bounds__(256, 1) void k_mega(
        const float* __restrict__ x, const float* __restrict__ wih0,
        const float* __restrict__ bih0, const float* __restrict__ bhh0,
        const float* __restrict__ whh0, const float* __restrict__ wih1,
        const float* __restrict__ whh1, const float* __restrict__ bi1,
        const float* __restrict__ bh1, _Float16* __restrict__ flatT) {
    __shared__ half8 Bl[2048];   // 32 KB Wih0 fragments
    const int tid = threadIdx.x;
    const int l = tid & 63;
    const int wv = tid >> 6;

    // ---- self-prep: Wih0 fragments -> Bl (validated mapping) ----
    #pragma unroll
    for (int q = 0; q < 8; ++q) {
        const int fi = q * 256 + tid;          // 0..2047
        const int c = fi >> 9;
        const int s = (fi >> 6) & 7;
        const int ll = fi & 63;
        const int row = c * 16 + (ll & 15);
        const int k0 = s * 32 + ((ll >> 4) << 3);
        const float* wp = wih0 + (size_t)row * DIN + k0;
        float4 a = *(const float4*)wp;
        float4 b = *(const float4*)(wp + 4);
        half8 h;
        h[0] = (_Float16)a.x; h[1] = (_Float16)a.y;
        h[2] = (_Float16)a.z; h[3] = (_Float16)a.w;
        h[4] = (_Float16)b.x; h[5] = (_Float16)b.y;
        h[6] = (_Float16)b.z; h[7] = (_Float16)b.w;
        Bl[fi] = h;
    }

    // ---- recurrence fragments + fused biases, per-thread ----
    half4 w0f[4], w1f[4], w2f[4];
    f32x4 b0[4], b1[4];
    #pragma unroll
    for (int c = 0; c < 4; ++c) {
        const int mrow = c * 16 + (l & 15);
        const int mk = (l >> 4) << 2;
        float4 v0 = *(const float4*)(whh0 + (size_t)mrow * HH + mk);
        w0f[c][0] = (_Float16)v0.x; w0f[c][1] = (_Float16)v0.y;
        w0f[c][2] = (_Float16)v0.z; w0f[c][3] = (_Float16)v0.w;
        float4 v1 = *(const float4*)(wih1 + (size_t)mrow * HH + mk);
        w1f[c][0] = (_Float16)v1.x; w1f[c][1] = (_Float16)v1.y;
        w1f[c][2] = (_Float16)v1.z; w1f[c][3] = (_Float16)v1.w;
        float4 v2 = *(const float4*)(whh1 + (size_t)mrow * HH + mk);
        w2f[c][0] = (_Float16)v2.x; w2f[c][1] = (_Float16)v2.y;
        w2f[c][2] = (_Float16)v2.z; w2f[c][3] = (_Float16)v2.w;
        const int bofs = c * 16 + mk;
        float4 vi0 = *(const float4*)(bih0 + bofs);
        float4 vh0 = *(const float4*)(bhh0 + bofs);
        b0[c][0] = vi0.x + vh0.x; b0[c][1] = vi0.y + vh0.y;
        b0[c][2] = vi0.z + vh0.z; b0[c][3] = vi0.w + vh0.w;
        float4 vi1 = *(const float4*)(bi1 + bofs);
        float4 vh1 = *(const float4*)(bh1 + bofs);
        b1[c][0] = vi1.x + vh1.x; b1[c][1] = vi1.y + vh1.y;
        b1[c][2] = vi1.z + vh1.z; b1[c][3] = vi1.w + vh1.w;
    }
    __syncthreads();   // Bl ready

    const int sb = blockIdx.x * 4 + wv;              // sample-group 0..1023
    const float* xp = x + (size_t)(sb * 16 + (l & 15)) * TT * DIN + ((l >> 4) << 3);

    f32x4 A0[8], B0[8], A1[8], B1[8];
    #pragma unroll
    for (int s = 0; s < 8; ++s) {
        A0[s] = *(const f32x4*)(xp + s * 32);
        B0[s] = *(const f32x4*)(xp + s * 32 + 4);
    }

    half4 h0f, h1f;
    #pragma unroll
    for (int j = 0; j < 4; ++j) { h0f[j] = (_Float16)0.0f; h1f[j] = (_Float16)0.0f; }
    f32x4 cs0 = (f32x4)0.0f, cs1 = (f32x4)0.0f;

#define STEP(t, CA, CB, NA, NB2)                                               \
    {                                                                          \
        if ((t) < 9) {                                                         \
            _Pragma("unroll")                                                  \
            for (int s = 0; s < 8; ++s) {                                      \
                NA[s] = *(const f32x4*)(xp + ((t) + 1) * DIN + s * 32);        \
                NB2[s] = *(const f32x4*)(xp + ((t) + 1) * DIN + s * 32 + 4);   \
            }                                                                  \
        }                                                                      \
        f32x4 ac0[4] = {b0[0], b0[1], b0[2], b0[3]};                           \
        _Pragma("unroll")                                                      \
        for (int s = 0; s < 8; ++s) {                                          \
            float fv[8] = {CA[s].x, CA[s].y, CA[s].z, CA[s].w,                 \
                           CB[s].x, CB[s].y, CB[s].z, CB[s].w};                \
            half8 xh, xl;                                                      \
            _Pragma("unroll")                                                  \
            for (int j = 0; j < 8; ++j) {                                      \
                _Float16 hi = (_Float16)fv[j];                                 \
                xh[j] = hi;                                                    \
                xl[j] = (_Float16)(fv[j] - (float)hi);                         \
            }                                                                  \
            _Pragma("unroll")                                                  \
            for (int c = 0; c < 4; ++c) {                                      \
                half8 wf = Bl[(c * 8 + s) * 64 + l];                           \
                ac0[c] = __builtin_amdgcn_mfma_f32_16x16x32_f16(wf, xh, ac0[c], 0, 0, 0); \
                ac0[c] = __builtin_amdgcn_mfma_f32_16x16x32_f16(wf, xl, ac0[c], 0, 0, 0); \
            }                                                                  \
        }                                                                      \
        _Pragma("unroll")                                                      \
        for (int c = 0; c < 4; ++c)                                            \
            ac0[c] = __builtin_amdgcn_mfma_f32_16x16x16f16(w0f[c], h0f, ac0[c], 0, 0, 0); \
        f32x4 h0v;                                                             \
        _Pragma("unroll")                                                      \
        for (int r = 0; r < 4; ++r) {                                          \
            float iv = sigf(ac0[0][r]), fg = sigf(ac0[1][r]);                  \
            float gv = tanhf_(ac0[2][r]), ov = sigf(ac0[3][r]);                \
            cs0[r] = fg * cs0[r] + iv * gv;                                    \
            h0v[r] = ov * tanhf_(cs0[r]);                                      \
        }                                                                      \
        h0f[0] = (_Float16)h0v[0]; h0f[1] = (_Float16)h0v[1];                  \
        h0f[2] = (_Float16)h0v[2]; h0f[3] = (_Float16)h0v[3];                  \
        f32x4 ac1[4] = {b1[0], b1[1], b1[2], b1[3]};                           \
        _Pragma("unroll")                                                      \
        for (int c = 0; c < 4; ++c) {                                          \
            ac1[c] = __builtin_amdgcn_mfma_f32_16x16x16f16(w1f[c], h0f, ac1[c], 0, 0, 0); \
            ac1[c] = __builtin_amdgcn_mfma_f32_16x16x16f16(w2f[c], h1f, ac1[c], 0, 0, 0); \
        }                                                                      \
        f32x4 h1v;                                                             \
        _Pragma("unroll")                                                      \
        for (int r = 0; r < 4; ++r) {                                          \
            float iv = sigf(ac1[0][r]), fg = sigf(ac1[1][r]);                  \
            float gv = tanhf_(ac1[2][r]), ov = sigf(ac1[3][r]);                \
            cs1[r] = fg * cs1[r] + iv * gv;                                    \
            h1v[r] = ov * tanhf_(cs1[r]);                                      \
        }                                                                      \
        h1f[0] = (_Float16)h1v[0]; h1f[1] = (_Float16)h1v[1];                  \
        h1f[2] = (_Float16)h1v[2]; h1f[3] = (_Float16)h1v[3];                  \
        _Pragma("unroll")                                                      \
        for (int r = 0; r < 4; ++r)                                            \
            flatT[(size_t)((t) * 16 + ((l >> 4) << 2) + r) * NB + sb * 16 + (l & 15)] = (_Float16)h1v[r]; \
    }

    STEP(0, A0, B0, A1, B1)
    STEP(1, A1, B1, A0, B0)
    STEP(2, A0, B0, A1, B1)
    STEP(3, A1, B1, A0, B0)
    STEP(4, A0, B0, A1, B1)
    STEP(5, A1, B1, A0, B0)
    STEP(6, A0, B0, A1, B1)
    STEP(7, A1, B1, A0, B0)
    STEP(8, A0, B0, A1, B1)
    STEP(9, A1, B1, A0, B0)
#undef STEP
}

// K2: BN stats directly from column-major flatT (coalesced).
__global__ __launch_bounds__(256) void k_bn(
        const _Float16* __restrict__ flatT, const float* __restrict__ gamma,
        const float* __restrict__ beta, float* __restrict__ scale,
        float* __restrict__ shift) {
    const int f = blockIdx.x;
    const int tid = threadIdx.x;
    const _Float16* col = flatT + (size_t)f * NB;
    float s = 0.0f, q = 0.0f;
    #pragma unroll 8
    for (int i = tid; i < NB; i += 256) {
        float v = (float)col[i];
        s += v; q += v * v;
    }
    #pragma unroll
    for (int o = 32; o > 0; o >>= 1) {
        s += __shfl_down(s, o, 64);
        q += __shfl_down(q, o, 64);
    }
    __shared__ float rs[4], rq[4];
    const int wv = tid >> 6;
    if ((tid & 63) == 0) { rs[wv] = s; rq[wv] = q; }
    __syncthreads();
    if (tid == 0) {
        float S = rs[0] + rs[1] + rs[2] + rs[3];
        float Q = rq[0] + rq[1] + rq[2] + rq[3];
        float mean = S * (1.0f / NB);
        float var = Q * (1.0f / NB) - mean * mean;
        float sc = gamma[f] * rsqrtf(var + 1e-5f);
        scale[f] = sc;
        shift[f] = beta[f] - mean * sc;
    }
}

// K3: BN-apply + LeakyReLU + concat + FC(162->2) + softmax.
__global__ __launch_bounds__(256) void k_fc(
        const _Float16* __restrict__ flatT, const float* __restrict__ scale,
        const float* __restrict__ shift, const float* __restrict__ ag,
        const float* __restrict__ fcw, const float* __restrict__ fcb,
        float* __restrict__ out) {
    const int smp = blockIdx.x * 256 + threadIdx.x;
    float p0 = 0.0f, p1 = 0.0f;
    #pragma unroll 8
    for (int f = 0; f < NF; ++f) {
        float xn = (float)flatT[(size_t)f * NB + smp] * scale[f] + shift[f];
        float a = xn >= 0.0f ? xn : 0.01f * xn;
        p0 += a * fcw[f];
        p1 += a * fcw[162 + f];
    }
    float a0 = ag[(size_t)smp * 2 + 0], a1 = ag[(size_t)smp * 2 + 1];
    float l0 = p0 + a0 * fcw[160] + a1 * fcw[161] + fcb[0];
    float l1 = p1 + a0 * fcw[162 + 160] + a1 * fcw[162 + 161] + fcb[1];
    float m = fmaxf(l0, l1);
    float e0 = __expf(l0 - m), e1 = __expf(l1 - m);
    float inv = 1.0f / (e0 + e1);
    out[(size_t)smp * 2 + 0] = e0 * inv;
    out[(size_t)smp * 2 + 1] = e1 * inv;
}

extern "C" void kernel_launch(void* const* d_in, const int* in_sizes, int n_in,
                              void* d_out, int out_size, void* d_ws, size_t ws_size,
                              hipStream_t stream) {
    const float* x     = (const float*)d_in[0];
    const float* ag    = (const float*)d_in[1];
    const float* wih0  = (const float*)d_in[2];
    const float* whh0  = (const float*)d_in[3];
    const float* bih0  = (const float*)d_in[4];
    const float* bhh0  = (const float*)d_in[5];
    const float* wih1  = (const float*)d_in[6];
    const float* whh1  = (const float*)d_in[7];
    const float* bih1  = (const float*)d_in[8];
    const float* bhh1  = (const float*)d_in[9];
    const float* gamma = (const float*)d_in[10];
    const float* beta  = (const float*)d_in[11];
    const float* fcw   = (const float*)d_in[12];
    const float* fcb   = (const float*)d_in[13];
    float* out = (float*)d_out;

    float* ws = (float*)d_ws;
    _Float16* flatT = (_Float16*)ws;   // [NF][NB] = 2,621,440 halfs = 1,310,720 f32 slots
    float* scale = ws + 1310720;       // 160 (after flatT's f32 footprint)
    float* shift = ws + 1310880;       // 160

    k_mega<<<dim3(256), dim3(256), 0, stream>>>(x, wih0, bih0, bhh0, whh0,
                                                wih1, whh1, bih1, bhh1, flatT);
    k_bn<<<dim3(NF),    dim3(256), 0, stream>>>(flatT, gamma, beta, scale, shift);
    k_fc<<<dim3(64),    dim3(256), 0, stream>>>(flatT, scale, shift, ag, fcw, fcb, out);
}